// Round 4
// baseline (596.897 us; speedup 1.0000x reference)
//
#include <hip/hip_runtime.h>
#include <math.h>

#define S_DIM 1024
#define B_DIM 16
#define K_DIM 1024
#define QD_DIM 1024
#define KD_DIM 1024
#define MASK_NEG (-3.0e38f)

using short8v = __attribute__((ext_vector_type(8))) short;
using float4v = __attribute__((ext_vector_type(4))) float;
using uint4v  = __attribute__((ext_vector_type(4))) uint;

#define MFMA(a, b, c) __builtin_amdgcn_mfma_f32_16x16x32_bf16(a, b, c, 0, 0, 0)
#define BAR()   __builtin_amdgcn_s_barrier()
#define SB0()   __builtin_amdgcn_sched_barrier(0)
#define PRIO(x) __builtin_amdgcn_s_setprio(x)
#define VMCNT(N) asm volatile("s_waitcnt vmcnt(" #N ")" ::: "memory")
#define LGKM0()  asm volatile("s_waitcnt lgkmcnt(0)" ::: "memory")

// ---------------------------------------------------------------------------
// helpers
// ---------------------------------------------------------------------------

// async global->LDS, 16 B per lane, dest = uniform base + lane*16 (linear)
__device__ __forceinline__ void gll16(const void* g, void* l) {
    __builtin_amdgcn_global_load_lds((const __attribute__((address_space(1))) unsigned int*)g,
                                     (__attribute__((address_space(3))) unsigned int*)l,
                                     16, 0, 0);
}

// fp32x4 -> bf16 hi (truncate) + bf16 of residual (truncate).
__device__ __forceinline__ void split4(const float4 v, uint2& hi, uint2& lo) {
    uint ax = __float_as_uint(v.x), ay = __float_as_uint(v.y);
    uint az = __float_as_uint(v.z), aw = __float_as_uint(v.w);
    hi.x = __builtin_amdgcn_perm(ay, ax, 0x07060302u);
    hi.y = __builtin_amdgcn_perm(aw, az, 0x07060302u);
    float rx = v.x - __uint_as_float(ax & 0xFFFF0000u);
    float ry = v.y - __uint_as_float(ay & 0xFFFF0000u);
    float rz = v.z - __uint_as_float(az & 0xFFFF0000u);
    float rw = v.w - __uint_as_float(aw & 0xFFFF0000u);
    lo.x = __builtin_amdgcn_perm(__float_as_uint(ry), __float_as_uint(rx), 0x07060302u);
    lo.y = __builtin_amdgcn_perm(__float_as_uint(rw), __float_as_uint(rz), 0x07060302u);
}

// LDS tile: 256 rows x 32 shorts (16 KB); slot = 16B unit; f(s) = s ^ ((s>>2)&7).
__device__ __forceinline__ int twiddle(int l) {
    int b0 = (l ^ (l >> 2) ^ (l >> 4)) & 1;
    int b1 = ((l >> 1) ^ (l >> 3)) & 1;
    int b2 = ((l >> 2) ^ (l >> 4)) & 1;
    return (l & 0x38) | (b2 << 2) | (b1 << 1) | b0;
}
__device__ __forceinline__ int fragoff(int R, int quad) {   // shorts
    return (((R << 2) | quad) ^ (R & 7)) << 3;
}

struct Ctx {
    int w, quad, l15, wm, wn, srow, scol;
    int arow, ac, ws0, ws1;
    int offA[4], offB[8];
};

__device__ __forceinline__ Ctx make_ctx(int t) {
    Ctx c;
    const int lane = t & 63;
    c.w = t >> 6; c.quad = lane >> 4; c.l15 = lane & 15;
    c.wm = c.w >> 1; c.wn = c.w & 1;
    const int sl = twiddle(lane);
    c.srow = c.w * 32 + (sl >> 2);
    c.scol = (sl & 3) * 8;
    c.arow = t >> 1; c.ac = t & 1;
    const int c0 = c.ac * 2;
    c.ws0 = ((c.arow << 2) | c0) ^ (c.arow & 7);
    c.ws1 = ((c.arow << 2) | (c0 + 1)) ^ (c.arow & 7);
    #pragma unroll
    for (int mt = 0; mt < 4; ++mt) { int R = c.wm * 64 + mt * 16 + c.l15; c.offA[mt] = fragoff(R, c.quad); }
    #pragma unroll
    for (int nt = 0; nt < 8; ++nt) { int R = c.wn * 128 + nt * 16 + c.l15; c.offB[nt] = fragoff(R, c.quad); }
    return c;
}

// Stage one 256x32 bf16 tile from a row-major [*][1024] plane; 2 gll16/thread.
__device__ __forceinline__ void stage2(const short* __restrict__ plane, int row0, int k0,
                                       short* tile, const Ctx& c) {
    const short* g0 = plane + (size_t)(row0 + c.srow) * 1024 + k0 + c.scol;
    gll16(g0, tile + c.w * 1024);
    gll16(g0 + (size_t)16 * 1024, tile + c.w * 1024 + 512);
}

__device__ __forceinline__ void mfma8x4(const short8v (&a)[4], const short8v (&bb)[8],
                                        float4v (&acc)[4][8]) {
    #pragma unroll
    for (int nt = 0; nt < 8; ++nt)
        #pragma unroll
        for (int mt = 0; mt < 4; ++mt)
            acc[mt][nt] = MFMA(a[mt], bb[nt], acc[mt][nt]);
}

// reg-staging: 4 float4 per thread = one 256x32 fp32 tile across 512 threads
__device__ __forceinline__ void load4(const float4* __restrict__ P, int kn, float4 (&v)[4]) {
    #pragma unroll
    for (int i = 0; i < 4; ++i) v[i] = P[kn / 4 + i];
}

// split + swizzled b128 ds_writes into hi/lo tiles (row arow, cols ac*16..+15)
__device__ __forceinline__ void write_split(const float4 (&va)[4], short* N0, short* N1,
                                            int ws0, int ws1) {
    uint2 h[4], l[4];
    #pragma unroll
    for (int i = 0; i < 4; ++i) split4(va[i], h[i], l[i]);
    uint4v v0, v1;
    v0[0] = h[0].x; v0[1] = h[0].y; v0[2] = h[1].x; v0[3] = h[1].y;
    v1[0] = h[2].x; v1[1] = h[2].y; v1[2] = h[3].x; v1[3] = h[3].y;
    *(uint4v*)(N0 + ws0 * 8) = v0;
    *(uint4v*)(N0 + ws1 * 8) = v1;
    v0[0] = l[0].x; v0[1] = l[0].y; v0[2] = l[1].x; v0[3] = l[1].y;
    v1[0] = l[2].x; v1[1] = l[2].y; v1[2] = l[3].x; v1[3] = l[3].y;
    *(uint4v*)(N1 + ws0 * 8) = v0;
    *(uint4v*)(N1 + ws1 * 8) = v1;
}

__device__ __forceinline__ void writeA_exp(const float4 (&va)[4], float Mv, float Lv,
                                           short* N0, short* N1, int ws0, int ws1) {
    float4 p[4];
    #pragma unroll
    for (int i = 0; i < 4; ++i) {
        p[i].x = __expf(va[i].x - Mv) * Lv;
        p[i].y = __expf(va[i].y - Mv) * Lv;
        p[i].z = __expf(va[i].z - Mv) * Lv;
        p[i].w = __expf(va[i].w - Mv) * Lv;
    }
    write_split(p, N0, N1, ws0, ws1);
}

// g3 B-transpose staging: thread (kq=t&7, dd=t>>3) owns a 4x4 block
// (k = kn+4kq.., d = dd*4..). Reads 4 float4 along d; writes 4 b64 along k.
__device__ __forceinline__ void loadT(const float* __restrict__ fB, int kn, float4 (&f)[4]) {
    #pragma unroll
    for (int i = 0; i < 4; ++i) f[i] = *(const float4*)(fB + (size_t)(kn + i) * 1024);
}
__device__ __forceinline__ void writeT(const float4 (&f)[4], short* N2, short* N3,
                                       int kq, int dd) {
    #pragma unroll
    for (int e = 0; e < 4; ++e) {
        float4 g;
        g.x = (&f[0].x)[e]; g.y = (&f[1].x)[e];
        g.z = (&f[2].x)[e]; g.w = (&f[3].x)[e];
        uint2 h, l;
        split4(g, h, l);
        const int R = dd * 4 + e;
        const int byteoff = ((((R << 2) | (kq >> 1)) ^ (R & 7)) << 4) + (kq & 1) * 8;
        *(uint2*)((char*)N2 + byteoff) = h;
        *(uint2*)((char*)N3 + byteoff) = l;
    }
}

// ---------------------------------------------------------------------------
// prep: W fp32 [1024][1024] -> bf16 hi/lo streams (only prep that pays: 4 MB
// reused by 256 g1 blocks).
// ---------------------------------------------------------------------------
__global__ __launch_bounds__(256) void k_split(const float* __restrict__ src,
                                               short* __restrict__ h, short* __restrict__ l) {
    const size_t base = ((size_t)blockIdx.x * 256 + threadIdx.x) * 4;
    const float4 v = *(const float4*)(src + base);
    uint2 hh, ll;
    split4(v, hh, ll);
    *(uint2*)(h + base) = hh;
    *(uint2*)(l + base) = ll;
}

__global__ __launch_bounds__(256) void k_stats(const float* __restrict__ alpha,
                                               float* __restrict__ mx,
                                               float* __restrict__ il) {
    const int r = blockIdx.x;
    const int t = threadIdx.x;
    const float4 v = ((const float4*)(alpha + (size_t)r * K_DIM))[t];
    float m = fmaxf(fmaxf(v.x, v.y), fmaxf(v.z, v.w));
    #pragma unroll
    for (int o = 1; o < 64; o <<= 1) m = fmaxf(m, __shfl_xor(m, o, 64));
    __shared__ float redm[4];
    __shared__ float reds[4];
    const int wid = t >> 6;
    if ((t & 63) == 0) redm[wid] = m;
    __syncthreads();
    const float M = fmaxf(fmaxf(redm[0], redm[1]), fmaxf(redm[2], redm[3]));
    float s = expf(v.x - M) + expf(v.y - M) + expf(v.z - M) + expf(v.w - M);
    #pragma unroll
    for (int o = 1; o < 64; o <<= 1) s += __shfl_xor(s, o, 64);
    if ((t & 63) == 0) reds[wid] = s;
    __syncthreads();
    if (t == 0) {
        mx[r] = M;
        il[r] = 1.0f / (reds[0] + reds[1] + reds[2] + reds[3]);
    }
}

// ---------------------------------------------------------------------------
// GEMM1: TQ[m][n] = sum_k Q[m][k]*W[n][k].  A = Q fp32 reg-staged;
// B = W pre-split via gll16.  vmcnt invariant entering P0: Bl(s)=2.
// ---------------------------------------------------------------------------
template<bool DS>
__device__ __forceinline__ void step_g1(const float4* __restrict__ qP, int kn,
                                        const short* __restrict__ Wh, const short* __restrict__ Wl, int n0,
                                        const short* C0, const short* C1, const short* C2, const short* C3,
                                        short* N0, short* N1, short* N2, short* N3,
                                        const Ctx& c, float4v (&acc)[4][8]) {
    short8v ah[4], bh[8];
    #pragma unroll
    for (int mt = 0; mt < 4; ++mt) ah[mt] = *(const short8v*)(C0 + c.offA[mt]);
    #pragma unroll
    for (int nt = 0; nt < 8; ++nt) bh[nt] = *(const short8v*)(C2 + c.offB[nt]);
    float4 qv[4];
    if (DS) { load4(qP, kn, qv); SB0(); stage2(Wh, n0, kn, N2, c); }
    SB0(); BAR(); LGKM0(); SB0();
    PRIO(1); mfma8x4(ah, bh, acc); PRIO(0); SB0(); BAR();

    short8v al[4];
    #pragma unroll
    for (int mt = 0; mt < 4; ++mt) al[mt] = *(const short8v*)(C1 + c.offA[mt]);
    if (DS) { stage2(Wl, n0, kn, N3, c); }
    SB0(); BAR(); LGKM0(); SB0();
    PRIO(1); mfma8x4(al, bh, acc); PRIO(0); SB0(); BAR();

    if (DS) { VMCNT(4); } else { VMCNT(0); }   // drains Bl(s)+qv; leaves Bh,Bl(s+1)
    SB0(); BAR();
    short8v bl[8];
    #pragma unroll
    for (int nt = 0; nt < 8; ++nt) bl[nt] = *(const short8v*)(C3 + c.offB[nt]);
    LGKM0(); SB0();
    PRIO(1); mfma8x4(ah, bl, acc); PRIO(0);
    if (DS) {
        write_split(qv, N0, N1, c.ws0, c.ws1);  // A(s+1) -> LDS
        LGKM0();
        VMCNT(2);                               // drains Bh(s+1); leaves Bl(s+1)=2
    }
    SB0(); BAR();
}

__global__ __launch_bounds__(512, 2) void g1k(const float* __restrict__ Q,
                                              const short* __restrict__ Wh, const short* __restrict__ Wl,
                                              short* __restrict__ TQh, short* __restrict__ TQl) {
    __shared__ __align__(16) short lds[65536];
    const int t = threadIdx.x;
    const int m0 = blockIdx.y * 256, n0 = blockIdx.x * 256;
    const Ctx c = make_ctx(t);
    const float4* qP = (const float4*)(Q + (size_t)(m0 + c.arow) * QD_DIM + c.ac * 16);
    short *T00 = lds,         *T01 = lds + 8192,  *T02 = lds + 16384, *T03 = lds + 24576;
    short *T10 = lds + 32768, *T11 = lds + 40960, *T12 = lds + 49152, *T13 = lds + 57344;

    float4v acc[4][8] = {};
    {   // prologue: tile 0
        float4 qv[4];
        load4(qP, 0, qv); SB0();
        stage2(Wh, n0, 0, T02, c);
        stage2(Wl, n0, 0, T03, c);
        VMCNT(4); SB0();                 // qv arrived; Bh0+Bl0 in flight
        write_split(qv, T00, T01, c.ws0, c.ws1);
        LGKM0();
        VMCNT(2); SB0();                 // Bh0 done; leaves Bl0=2
        BAR();
    }
    #pragma unroll 1
    for (int it = 0; it < 15; ++it) {
        step_g1<true>(qP, (2 * it + 1) * 32, Wh, Wl, n0, T00, T01, T02, T03, T10, T11, T12, T13, c, acc);
        step_g1<true>(qP, (2 * it + 2) * 32, Wh, Wl, n0, T10, T11, T12, T13, T00, T01, T02, T03, c, acc);
    }
    step_g1<true >(qP, 31 * 32, Wh, Wl, n0, T00, T01, T02, T03, T10, T11, T12, T13, c, acc);
    step_g1<false>(qP, 0,       Wh, Wl, n0, T10, T11, T12, T13, T00, T01, T02, T03, c, acc);

    #pragma unroll
    for (int mt = 0; mt < 4; ++mt)
        #pragma unroll
        for (int reg = 0; reg < 4; ++reg) {
            const int m = m0 + c.wm * 64 + mt * 16 + c.quad * 4 + reg;
            const int s = m >> 4, bq = m & 15;
            short* th = TQh + (size_t)bq * 1048576 + (size_t)s * 1024;
            short* tl = TQl + (size_t)bq * 1048576 + (size_t)s * 1024;
            #pragma unroll
            for (int nt = 0; nt < 8; ++nt) {
                const int n = n0 + c.wn * 128 + nt * 16 + c.l15;
                const float x = acc[mt][nt][reg];
                const uint u = __float_as_uint(x);
                th[n] = (short)(u >> 16);
                const float r2 = x - __uint_as_float(u & 0xFFFF0000u);
                tl[n] = (short)(__float_as_uint(r2) >> 16);
            }
        }
}

// ---------------------------------------------------------------------------
// GEMM2 (per b): alpha[s][b][k] = sum_d TQ[b][s][d]*keys[b][k][d], + mask.
// A = TQ pre-split via gll16; B = keys fp32 reg-staged.
// vmcnt invariant entering P0: Al(s)=2.
// ---------------------------------------------------------------------------
template<bool DS>
__device__ __forceinline__ void step_g2(const float4* __restrict__ kP, int kn,
                                        const short* __restrict__ Ahp, const short* __restrict__ Alp, int m0,
                                        const short* C0, const short* C1, const short* C2, const short* C3,
                                        short* N0, short* N1, short* N2, short* N3,
                                        const Ctx& c, float4v (&acc)[4][8]) {
    short8v ah[4], bh[8];
    #pragma unroll
    for (int mt = 0; mt < 4; ++mt) ah[mt] = *(const short8v*)(C0 + c.offA[mt]);
    #pragma unroll
    for (int nt = 0; nt < 8; ++nt) bh[nt] = *(const short8v*)(C2 + c.offB[nt]);
    float4 kv[4];
    if (DS) { load4(kP, kn, kv); SB0(); stage2(Ahp, m0, kn, N0, c); VMCNT(6); }
    else    { VMCNT(0); }                      // drains Al(s) before P1's read-barrier
    SB0(); BAR(); LGKM0(); SB0();
    PRIO(1); mfma8x4(ah, bh, acc); PRIO(0); SB0(); BAR();

    short8v al[4];
    #pragma unroll
    for (int mt = 0; mt < 4; ++mt) al[mt] = *(const short8v*)(C1 + c.offA[mt]);
    if (DS) { stage2(Alp, m0, kn, N1, c); }
    SB0(); BAR(); LGKM0(); SB0();
    PRIO(1); mfma8x4(al, bh, acc); PRIO(0); SB0(); BAR();

    if (DS) { VMCNT(4); } else { VMCNT(0); }   // drains kv; leaves Ah,Al(s+1)
    SB0(); BAR();
    short8v bl[8];
    #pragma unroll
    for (int nt = 0; nt < 8; ++nt) bl[nt] = *(const short8v*)(C3 + c.offB[nt]);
    LGKM0(); SB0();
    PRIO(1); mfma8x4(ah, bl, acc); PRIO(0);
    if (DS) {
        write_split(kv, N2, N3, c.ws0, c.ws1);  // B(s+1) -> LDS
        LGKM0();
        VMCNT(2);                               // drains Ah(s+1); leaves Al(s+1)=2
    }
    SB0(); BAR();
}

__global__ __launch_bounds__(512, 2) void g2k(const short* __restrict__ TQh, const short* __restrict__ TQl,
                                              const float* __restrict__ keys,
                                              const int* __restrict__ mask, float* __restrict__ alpha) {
    __shared__ __align__(16) short lds[65536];
    const int t = threadIdx.x;
    const int m0 = blockIdx.y * 256, n0 = blockIdx.x * 256, b = blockIdx.z;
    const Ctx c = make_ctx(t);
    const short* Ahp = TQh + (size_t)b * 1048576;
    const short* Alp = TQl + (size_t)b * 1048576;
    const float* Kb = keys + (size_t)b * K_DIM * KD_DIM;
    const float4* kP = (const float4*)(Kb + (size_t)(n0 + c.arow) * KD_DIM + c.ac * 16);
    short *T00 = lds,         *T01 = lds + 8192,  *T02 = lds + 16384, *T03 = lds + 24576;
    short *T10 = lds + 32768, *T11 = lds + 40960, *T12 = lds + 49152, *T13 = lds + 57344;

    float4v acc[4][8] = {};
    {   // prologue: tile 0
        float4 kv[4];
        load4(kP, 0, kv); SB0();
        stage2(Ahp, m0, 0, T00, c);
        VMCNT(2); SB0();                 // kv arrived; Ah0 in flight
        write_split(kv, T02, T03, c.ws0, c.ws1);
        LGKM0(); SB0();
        stage2(Alp, m0, 0, T01, c);
        VMCNT(2); SB0();                 // Ah0 done; leaves Al0=2
        BAR();
    }
    #pragma unroll 1
    for (int it = 0; it < 15; ++it) {
        step_g2<true>(kP, (2 * it + 1) * 32, Ahp, Alp, m0, T00, T01, T02, T03, T10, T11, T12, T13, c, acc);
        step_g2<true>(kP, (2 * it + 2) * 32, Ahp, Alp, m0, T10, T11, T12, T13, T00, T01, T02, T03, c, acc);
    }
    step_g2<true >(kP, 31 * 32, Ahp, Alp, m0, T00, T01, T02, T03, T10, T11, T12, T13, c, acc);
    step_g2<false>(kP, 0,       Ahp, Alp, m0, T10, T11, T12, T13, T00, T01, T02, T03, c, acc);

    int mk[8];
    #pragma unroll
    for (int nt = 0; nt < 8; ++nt)
        mk[nt] = mask[b * K_DIM + n0 + c.wn * 128 + nt * 16 + c.l15];
    #pragma unroll
    for (int mt = 0; mt < 4; ++mt)
        #pragma unroll
        for (int reg = 0; reg < 4; ++reg) {
            const int m = m0 + c.wm * 64 + mt * 16 + c.quad * 4 + reg;
            #pragma unroll
            for (int nt = 0; nt < 8; ++nt) {
                const int n = n0 + c.wn * 128 + nt * 16 + c.l15;
                alpha[((size_t)m * B_DIM + b) * K_DIM + n] = mk[nt] ? MASK_NEG : acc[mt][nt][reg];
            }
        }
}

// ---------------------------------------------------------------------------
// GEMM3 (per b): out[s][b][d] = sum_k P[s][k]*keys[b][k][d].
// A = alpha reg-staged (exp on the fly); B = keys fp32 transposed in-kernel.
// No gll16; vmcnt tracks only the 8 reg loads; invariant entering P0: 0.
// ---------------------------------------------------------------------------
template<bool DS>
__device__ __forceinline__ void step_g3(const float4* __restrict__ aP, const float* __restrict__ fB, int kn,
                                        const short* C0, const short* C1, const short* C2, const short* C3,
                                        short* N0, short* N1, short* N2, short* N3,
                                        const Ctx& c, float Mv, float Lv, int kq, int dd,
                                        float4v (&acc)[4][8]) {
    short8v ah[4], bh[8];
    #pragma unroll
    for (int mt = 0; mt < 4; ++mt) ah[mt] = *(const short8v*)(C0 + c.offA[mt]);
    #pragma unroll
    for (int nt = 0; nt < 8; ++nt) bh[nt] = *(const short8v*)(C2 + c.offB[nt]);
    float4 av[4];
    if (DS) { load4(aP, kn, av); }
    SB0(); BAR(); LGKM0(); SB0();
    PRIO(1); mfma8x4(ah, bh, acc); PRIO(0); SB0(); BAR();

    short8v al[4];
    #pragma unroll
    for (int mt = 0; mt < 4; ++mt) al[mt] = *(const short8v*)(C1 + c.offA[mt]);
    float4 f[4];
    if (DS) { loadT(fB, kn, f); }
    SB0(); BAR(); LGKM0(); SB0();
    PRIO(1); mfma8x4(al, bh, acc); PRIO(0); SB0(); BAR();

    VMCNT(0);                                  // av+f arrived (2 phases of slack)
    SB0(); BAR();
    short8v bl[8];
    #pragma unroll
    for (int nt = 0; nt < 8; ++nt) bl[nt] = *(const short8v*)(C3 + c.offB[nt]);
    LGKM0(); SB0();
    PRIO(1); mfma8x4(ah, bl, acc); PRIO(0);
    if (DS) {
        writeA_exp(av, Mv, Lv, N0, N1, c.ws0, c.ws1);
        writeT(f, N2, N3, kq, dd);
        LGKM0();
    }
    SB0(); BAR();
}

__global__ __launch_bounds__(512, 2) void g3k(const float* __restrict__ alpha,
                                              const float* __restrict__ keys,
                                              const float* __restrict__ mx, const float* __restrict__ il,
                                              float* __restrict__ outk) {
    __shared__ __align__(16) short lds[65536];
    const int t = threadIdx.x;
    const int m0 = blockIdx.y * 256, n0 = blockIdx.x * 256, b = blockIdx.z;
    const Ctx c = make_ctx(t);
    const float* Kb = keys + (size_t)b * K_DIM * KD_DIM;
    const float4* aP = (const float4*)(alpha + ((size_t)(m0 + c.arow) * B_DIM + b) * K_DIM + c.ac * 16);
    const float Mv = mx[(size_t)(m0 + c.arow) * B_DIM + b];
    const float Lv = il[(size_t)(m0 + c.arow) * B_DIM + b];
    const int kq = t & 7, dd = t >> 3;
    const float* fB = Kb + (size_t)(4 * kq) * KD_DIM + n0 + dd * 4;
    short *T00 = lds,         *T01 = lds + 8192,  *T02 = lds + 16384, *T03 = lds + 24576;
    short *T10 = lds + 32768, *T11 = lds + 40960, *T12 = lds + 49152, *T13 = lds + 57344;

    float4v acc[4][8] = {};
    {   // prologue: tile 0
        float4 av[4], f[4];
        load4(aP, 0, av); SB0();
        loadT(fB, 0, f);
        VMCNT(0); SB0();
        writeA_exp(av, Mv, Lv, T00, T01, c.ws0, c.ws1);
        writeT(f, T02, T03, kq, dd);
        LGKM0(); SB0();
        BAR();
    }
    #pragma unroll 1
    for (int it = 0; it < 15; ++it) {
        step_g3<true>(aP, fB, (2 * it + 1) * 32, T00, T01, T02, T03, T10, T11, T12, T13, c, Mv, Lv, kq, dd, acc);
        step_g3<true>(aP, fB, (2 * it + 2) * 32, T10, T11, T12, T13, T00, T01, T02, T03, c, Mv, Lv, kq, dd, acc);
    }
    step_g3<true >(aP, fB, 31 * 32, T00, T01, T02, T03, T10, T11, T12, T13, c, Mv, Lv, kq, dd, acc);
    step_g3<false>(aP, fB, 0,       T10, T11, T12, T13, T00, T01, T02, T03, c, Mv, Lv, kq, dd, acc);

    #pragma unroll
    for (int mt = 0; mt < 4; ++mt)
        #pragma unroll
        for (int reg = 0; reg < 4; ++reg) {
            const int m = m0 + c.wm * 64 + mt * 16 + c.quad * 4 + reg;
            #pragma unroll
            for (int nt = 0; nt < 8; ++nt) {
                const int n = n0 + c.wn * 128 + nt * 16 + c.l15;
                outk[((size_t)m * B_DIM + b) * KD_DIM + n] = acc[mt][nt][reg];
            }
        }
}

// ---------------------------------------------------------------------------
extern "C" void kernel_launch(void* const* d_in, const int* in_sizes, int n_in,
                              void* d_out, int out_size, void* d_ws, size_t ws_size,
                              hipStream_t stream) {
    const float* Q    = (const float*)d_in[0];   // (S, B, QD)
    const float* keys = (const float*)d_in[1];   // (B, K, KD)
    const int*   mask = (const int*)d_in[2];     // (B, K)
    const float* W    = (const float*)d_in[3];   // (KD, QD)

    float* out_att   = (float*)d_out;
    float* out_alpha = out_att + (size_t)S_DIM * B_DIM * KD_DIM;

    const size_t STREAM = (size_t)B_DIM * 1048576;   // shorts per TQ stream (32 MiB)

    // ws: TQh/TQl (64 MiB) + mx/il (128 KiB) — proven footprint.
    short* TQh = (short*)d_ws;
    short* TQl = TQh + STREAM;
    float* mx  = (float*)((char*)d_ws + ((size_t)64 << 20));
    float* il  = mx + S_DIM * B_DIM;

    // W bf16 streams (4 MiB) live at the head of out_att: dead by the time
    // g3 writes the real output there (g1 is the only reader, g3 runs last).
    short* Wh = (short*)out_att;
    short* Wl = Wh + 1048576;

    dim3 blk(256), blkg(512);

    k_split<<<dim3(1024), blk, 0, stream>>>(W, Wh, Wl);

    g1k<<<dim3(KD_DIM / 256, (S_DIM * B_DIM) / 256), blkg, 0, stream>>>(Q, Wh, Wl, TQh, TQl);

    g2k<<<dim3(K_DIM / 256, S_DIM / 256, B_DIM), blkg, 0, stream>>>(TQh, TQl, keys, mask, out_alpha);

    k_stats<<<dim3(S_DIM * B_DIM), blk, 0, stream>>>(out_alpha, mx, il);

    g3k<<<dim3(KD_DIM / 256, S_DIM / 256, B_DIM), blkg, 0, stream>>>(out_alpha, keys, mx, il, out_att);
}

// Round 5
// 553.199 us; speedup vs baseline: 1.0790x; 1.0790x over previous
//
#include <hip/hip_runtime.h>
#include <math.h>

#define S_DIM 1024
#define B_DIM 16
#define K_DIM 1024
#define QD_DIM 1024
#define KD_DIM 1024
#define MASK_NEG (-3.0e38f)

using short8v = __attribute__((ext_vector_type(8))) short;
using float4v = __attribute__((ext_vector_type(4))) float;
using uint4v  = __attribute__((ext_vector_type(4))) uint;

#define MFMA(a, b, c) __builtin_amdgcn_mfma_f32_16x16x32_bf16(a, b, c, 0, 0, 0)
#define BAR()   __builtin_amdgcn_s_barrier()
#define SB0()   __builtin_amdgcn_sched_barrier(0)
#define PRIO(x) __builtin_amdgcn_s_setprio(x)
#define VMCNT(N) asm volatile("s_waitcnt vmcnt(" #N ")" ::: "memory")
#define LGKM0()  asm volatile("s_waitcnt lgkmcnt(0)" ::: "memory")

// ---------------------------------------------------------------------------
// helpers
// ---------------------------------------------------------------------------

// async global->LDS, 16 B per lane, dest = uniform base + lane*16 (linear)
__device__ __forceinline__ void gll16(const void* g, void* l) {
    __builtin_amdgcn_global_load_lds((const __attribute__((address_space(1))) unsigned int*)g,
                                     (__attribute__((address_space(3))) unsigned int*)l,
                                     16, 0, 0);
}

// fp32x4 -> bf16 hi (truncate) + bf16 of residual (truncate).
__device__ __forceinline__ void split4(const float4 v, uint2& hi, uint2& lo) {
    uint ax = __float_as_uint(v.x), ay = __float_as_uint(v.y);
    uint az = __float_as_uint(v.z), aw = __float_as_uint(v.w);
    hi.x = __builtin_amdgcn_perm(ay, ax, 0x07060302u);
    hi.y = __builtin_amdgcn_perm(aw, az, 0x07060302u);
    float rx = v.x - __uint_as_float(ax & 0xFFFF0000u);
    float ry = v.y - __uint_as_float(ay & 0xFFFF0000u);
    float rz = v.z - __uint_as_float(az & 0xFFFF0000u);
    float rw = v.w - __uint_as_float(aw & 0xFFFF0000u);
    lo.x = __builtin_amdgcn_perm(__float_as_uint(ry), __float_as_uint(rx), 0x07060302u);
    lo.y = __builtin_amdgcn_perm(__float_as_uint(rw), __float_as_uint(rz), 0x07060302u);
}

// LDS tile: 256 rows x 32 shorts (16 KB); slot = 16B unit; f(s) = s ^ ((s>>2)&7).
__device__ __forceinline__ int twiddle(int l) {
    int b0 = (l ^ (l >> 2) ^ (l >> 4)) & 1;
    int b1 = ((l >> 1) ^ (l >> 3)) & 1;
    int b2 = ((l >> 2) ^ (l >> 4)) & 1;
    return (l & 0x38) | (b2 << 2) | (b1 << 1) | b0;
}
__device__ __forceinline__ int fragoff(int R, int quad) {   // shorts
    return (((R << 2) | quad) ^ (R & 7)) << 3;
}

struct Ctx {
    int w, quad, l15, wm, wn, srow, scol;
    int arow, ac, ws0, ws1;
    int offA[4], offB[8];
};

__device__ __forceinline__ Ctx make_ctx(int t) {
    Ctx c;
    const int lane = t & 63;
    c.w = t >> 6; c.quad = lane >> 4; c.l15 = lane & 15;
    c.wm = c.w >> 1; c.wn = c.w & 1;
    const int sl = twiddle(lane);
    c.srow = c.w * 32 + (sl >> 2);
    c.scol = (sl & 3) * 8;
    c.arow = t >> 1; c.ac = t & 1;
    const int c0 = c.ac * 2;
    c.ws0 = ((c.arow << 2) | c0) ^ (c.arow & 7);
    c.ws1 = ((c.arow << 2) | (c0 + 1)) ^ (c.arow & 7);
    #pragma unroll
    for (int mt = 0; mt < 4; ++mt) { int R = c.wm * 64 + mt * 16 + c.l15; c.offA[mt] = fragoff(R, c.quad); }
    #pragma unroll
    for (int nt = 0; nt < 8; ++nt) { int R = c.wn * 128 + nt * 16 + c.l15; c.offB[nt] = fragoff(R, c.quad); }
    return c;
}

// Stage one 256x32 bf16 tile from a row-major [*][1024] plane; 2 gll16/thread.
__device__ __forceinline__ void stage2(const short* __restrict__ plane, int row0, int k0,
                                       short* tile, const Ctx& c) {
    const short* g0 = plane + (size_t)(row0 + c.srow) * 1024 + k0 + c.scol;
    gll16(g0, tile + c.w * 1024);
    gll16(g0 + (size_t)16 * 1024, tile + c.w * 1024 + 512);
}

__device__ __forceinline__ void mfma8x4(const short8v (&a)[4], const short8v (&bb)[8],
                                        float4v (&acc)[4][8]) {
    #pragma unroll
    for (int nt = 0; nt < 8; ++nt)
        #pragma unroll
        for (int mt = 0; mt < 4; ++mt)
            acc[mt][nt] = MFMA(a[mt], bb[nt], acc[mt][nt]);
}

// reg-staging: 4 float4 per thread = one 256x32 fp32 tile across 512 threads
__device__ __forceinline__ void load4(const float4* __restrict__ P, int kn, float4 (&v)[4]) {
    #pragma unroll
    for (int i = 0; i < 4; ++i) v[i] = P[kn / 4 + i];
}

// split + swizzled b128 ds_writes into hi/lo tiles (row arow, cols ac*16..+15)
__device__ __forceinline__ void write_split(const float4 (&va)[4], short* N0, short* N1,
                                            int ws0, int ws1) {
    uint2 h[4], l[4];
    #pragma unroll
    for (int i = 0; i < 4; ++i) split4(va[i], h[i], l[i]);
    uint4v v0, v1;
    v0[0] = h[0].x; v0[1] = h[0].y; v0[2] = h[1].x; v0[3] = h[1].y;
    v1[0] = h[2].x; v1[1] = h[2].y; v1[2] = h[3].x; v1[3] = h[3].y;
    *(uint4v*)(N0 + ws0 * 8) = v0;
    *(uint4v*)(N0 + ws1 * 8) = v1;
    v0[0] = l[0].x; v0[1] = l[0].y; v0[2] = l[1].x; v0[3] = l[1].y;
    v1[0] = l[2].x; v1[1] = l[2].y; v1[2] = l[3].x; v1[3] = l[3].y;
    *(uint4v*)(N1 + ws0 * 8) = v0;
    *(uint4v*)(N1 + ws1 * 8) = v1;
}

__device__ __forceinline__ void writeA_exp(const float4 (&va)[4], float Mv, float Lv,
                                           short* N0, short* N1, int ws0, int ws1) {
    float4 p[4];
    #pragma unroll
    for (int i = 0; i < 4; ++i) {
        p[i].x = __expf(va[i].x - Mv) * Lv;
        p[i].y = __expf(va[i].y - Mv) * Lv;
        p[i].z = __expf(va[i].z - Mv) * Lv;
        p[i].w = __expf(va[i].w - Mv) * Lv;
    }
    write_split(p, N0, N1, ws0, ws1);
}

// ---------------------------------------------------------------------------
// prep kernels
// ---------------------------------------------------------------------------
__global__ __launch_bounds__(256) void k_split(const float* __restrict__ src,
                                               short* __restrict__ h, short* __restrict__ l) {
    const size_t base = ((size_t)blockIdx.x * 256 + threadIdx.x) * 4;
    const float4 v = *(const float4*)(src + base);
    uint2 hh, ll;
    split4(v, hh, ll);
    *(uint2*)(h + base) = hh;
    *(uint2*)(l + base) = ll;
}

__global__ __launch_bounds__(256) void k_transpose(const float* __restrict__ keys,
                                                   short* __restrict__ th, short* __restrict__ tl) {
    __shared__ float T[32][33];
    const int t = threadIdx.x;
    const int b = blockIdx.z, d0 = blockIdx.x * 32, k0 = blockIdx.y * 32;
    const float* Kb = keys + (size_t)b * K_DIM * KD_DIM;
    const int ry = t >> 3, cx = (t & 7) * 4;
    const float4 v = *(const float4*)(Kb + (size_t)(k0 + ry) * KD_DIM + d0 + cx);
    T[ry][cx] = v.x; T[ry][cx + 1] = v.y; T[ry][cx + 2] = v.z; T[ry][cx + 3] = v.w;
    __syncthreads();
    float4 g;
    g.x = T[cx][ry]; g.y = T[cx + 1][ry]; g.z = T[cx + 2][ry]; g.w = T[cx + 3][ry];
    uint2 hh, ll;
    split4(g, hh, ll);
    const size_t o = (size_t)b * K_DIM * KD_DIM + (size_t)(d0 + ry) * K_DIM + k0 + cx;
    *(uint2*)(th + o) = hh;
    *(uint2*)(tl + o) = ll;
}

__global__ __launch_bounds__(256) void k_stats(const float* __restrict__ alpha,
                                               float* __restrict__ mx,
                                               float* __restrict__ il) {
    const int r = blockIdx.x;
    const int t = threadIdx.x;
    const float4 v = ((const float4*)(alpha + (size_t)r * K_DIM))[t];
    float m = fmaxf(fmaxf(v.x, v.y), fmaxf(v.z, v.w));
    #pragma unroll
    for (int o = 1; o < 64; o <<= 1) m = fmaxf(m, __shfl_xor(m, o, 64));
    __shared__ float redm[4];
    __shared__ float reds[4];
    const int wid = t >> 6;
    if ((t & 63) == 0) redm[wid] = m;
    __syncthreads();
    const float M = fmaxf(fmaxf(redm[0], redm[1]), fmaxf(redm[2], redm[3]));
    float s = expf(v.x - M) + expf(v.y - M) + expf(v.z - M) + expf(v.w - M);
    #pragma unroll
    for (int o = 1; o < 64; o <<= 1) s += __shfl_xor(s, o, 64);
    if ((t & 63) == 0) reds[wid] = s;
    __syncthreads();
    if (t == 0) {
        mx[r] = M;
        il[r] = 1.0f / (reds[0] + reds[1] + reds[2] + reds[3]);
    }
}

// ---------------------------------------------------------------------------
// GEMM1: TQ[m][n] = sum_k Q[m][k]*W[n][k].  A = Q fp32 reg-staged;
// B = W pre-split via gll16.  vmcnt invariant entering P0: Bl(s)=2.
// (round-4 core: harness-proven correct)
// ---------------------------------------------------------------------------
template<bool DS>
__device__ __forceinline__ void step_g1(const float4* __restrict__ qP, int kn,
                                        const short* __restrict__ Wh, const short* __restrict__ Wl, int n0,
                                        const short* C0, const short* C1, const short* C2, const short* C3,
                                        short* N0, short* N1, short* N2, short* N3,
                                        const Ctx& c, float4v (&acc)[4][8]) {
    short8v ah[4], bh[8];
    #pragma unroll
    for (int mt = 0; mt < 4; ++mt) ah[mt] = *(const short8v*)(C0 + c.offA[mt]);
    #pragma unroll
    for (int nt = 0; nt < 8; ++nt) bh[nt] = *(const short8v*)(C2 + c.offB[nt]);
    float4 qv[4];
    if (DS) { load4(qP, kn, qv); SB0(); stage2(Wh, n0, kn, N2, c); }
    SB0(); BAR(); LGKM0(); SB0();
    PRIO(1); mfma8x4(ah, bh, acc); PRIO(0); SB0(); BAR();

    short8v al[4];
    #pragma unroll
    for (int mt = 0; mt < 4; ++mt) al[mt] = *(const short8v*)(C1 + c.offA[mt]);
    if (DS) { stage2(Wl, n0, kn, N3, c); }
    SB0(); BAR(); LGKM0(); SB0();
    PRIO(1); mfma8x4(al, bh, acc); PRIO(0); SB0(); BAR();

    if (DS) { VMCNT(4); } else { VMCNT(0); }   // drains Bl(s)+qv; leaves Bh,Bl(s+1)
    SB0(); BAR();
    short8v bl[8];
    #pragma unroll
    for (int nt = 0; nt < 8; ++nt) bl[nt] = *(const short8v*)(C3 + c.offB[nt]);
    LGKM0(); SB0();
    PRIO(1); mfma8x4(ah, bl, acc); PRIO(0);
    if (DS) {
        write_split(qv, N0, N1, c.ws0, c.ws1);  // A(s+1) -> LDS
        LGKM0();
        VMCNT(2);                               // drains Bh(s+1); leaves Bl(s+1)=2
    }
    SB0(); BAR();
}

__global__ __launch_bounds__(512, 2) void g1k(const float* __restrict__ Q,
                                              const short* __restrict__ Wh, const short* __restrict__ Wl,
                                              short* __restrict__ TQh, short* __restrict__ TQl) {
    __shared__ __align__(16) short lds[65536];
    const int t = threadIdx.x;
    const int m0 = blockIdx.y * 256, n0 = blockIdx.x * 256;
    const Ctx c = make_ctx(t);
    const float4* qP = (const float4*)(Q + (size_t)(m0 + c.arow) * QD_DIM + c.ac * 16);
    short *T00 = lds,         *T01 = lds + 8192,  *T02 = lds + 16384, *T03 = lds + 24576;
    short *T10 = lds + 32768, *T11 = lds + 40960, *T12 = lds + 49152, *T13 = lds + 57344;

    float4v acc[4][8] = {};
    {   // prologue: tile 0
        float4 qv[4];
        load4(qP, 0, qv); SB0();
        stage2(Wh, n0, 0, T02, c);
        stage2(Wl, n0, 0, T03, c);
        VMCNT(4); SB0();                 // qv arrived; Bh0+Bl0 in flight
        write_split(qv, T00, T01, c.ws0, c.ws1);
        LGKM0();
        VMCNT(2); SB0();                 // Bh0 done; leaves Bl0=2
        BAR();
    }
    #pragma unroll 1
    for (int it = 0; it < 15; ++it) {
        step_g1<true>(qP, (2 * it + 1) * 32, Wh, Wl, n0, T00, T01, T02, T03, T10, T11, T12, T13, c, acc);
        step_g1<true>(qP, (2 * it + 2) * 32, Wh, Wl, n0, T10, T11, T12, T13, T00, T01, T02, T03, c, acc);
    }
    step_g1<true >(qP, 31 * 32, Wh, Wl, n0, T00, T01, T02, T03, T10, T11, T12, T13, c, acc);
    step_g1<false>(qP, 0,       Wh, Wl, n0, T10, T11, T12, T13, T00, T01, T02, T03, c, acc);

    #pragma unroll
    for (int mt = 0; mt < 4; ++mt)
        #pragma unroll
        for (int reg = 0; reg < 4; ++reg) {
            const int m = m0 + c.wm * 64 + mt * 16 + c.quad * 4 + reg;
            const int s = m >> 4, bq = m & 15;
            short* th = TQh + (size_t)bq * 1048576 + (size_t)s * 1024;
            short* tl = TQl + (size_t)bq * 1048576 + (size_t)s * 1024;
            #pragma unroll
            for (int nt = 0; nt < 8; ++nt) {
                const int n = n0 + c.wn * 128 + nt * 16 + c.l15;
                const float x = acc[mt][nt][reg];
                const uint u = __float_as_uint(x);
                th[n] = (short)(u >> 16);
                const float r2 = x - __uint_as_float(u & 0xFFFF0000u);
                tl[n] = (short)(__float_as_uint(r2) >> 16);
            }
        }
}

// ---------------------------------------------------------------------------
// GEMM2 (per b): alpha[s][b][k] = sum_d TQ[b][s][d]*keys[b][k][d], + mask.
// All four streams via gll16 (round-3 core: proven 105-110 us).
// Steady-state invariant entering P0: outstanding vmem = AlBl(tile s) = 4.
// ---------------------------------------------------------------------------
template<bool DS>
__device__ __forceinline__ void step_gg(const short* __restrict__ Ahp, const short* __restrict__ Alp,
                                        const short* __restrict__ Bhp, const short* __restrict__ Blp,
                                        int m0, int n0, int kn,
                                        const short* C0, const short* C1, const short* C2, const short* C3,
                                        short* N0, short* N1, short* N2, short* N3,
                                        const Ctx& c, float4v (&acc)[4][8]) {
    short8v ah[4], bh[8];
    #pragma unroll
    for (int mt = 0; mt < 4; ++mt) ah[mt] = *(const short8v*)(C0 + c.offA[mt]);
    #pragma unroll
    for (int nt = 0; nt < 8; ++nt) bh[nt] = *(const short8v*)(C2 + c.offB[nt]);
    if (DS) { stage2(Ahp, m0, kn, N0, c); stage2(Bhp, n0, kn, N2, c); VMCNT(4); }
    else    { VMCNT(0); }
    SB0(); BAR(); LGKM0(); SB0();
    PRIO(1); mfma8x4(ah, bh, acc); PRIO(0); SB0(); BAR();

    short8v al[4];
    #pragma unroll
    for (int mt = 0; mt < 4; ++mt) al[mt] = *(const short8v*)(C1 + c.offA[mt]);
    if (DS) { stage2(Alp, m0, kn, N1, c); stage2(Blp, n0, kn, N3, c); }
    SB0(); BAR(); LGKM0(); SB0();
    PRIO(1); mfma8x4(al, bh, acc); PRIO(0); SB0(); BAR();

    short8v bl[8];
    #pragma unroll
    for (int nt = 0; nt < 8; ++nt) bl[nt] = *(const short8v*)(C3 + c.offB[nt]);
    if (DS) { VMCNT(4); }   // drains AhBh(s+1) -> validates next P0; leaves AlBl(s+1)=4
    SB0(); BAR(); LGKM0(); SB0();
    PRIO(1); mfma8x4(ah, bl, acc); PRIO(0); SB0(); BAR();
}

__device__ __forceinline__ void core_gg(const short* __restrict__ Ahp, const short* __restrict__ Alp,
                                        const short* __restrict__ Bhp, const short* __restrict__ Blp,
                                        int m0, int n0, short* lds, const Ctx& c, float4v (&acc)[4][8]) {
    short *T00 = lds,         *T01 = lds + 8192,  *T02 = lds + 16384, *T03 = lds + 24576;
    short *T10 = lds + 32768, *T11 = lds + 40960, *T12 = lds + 49152, *T13 = lds + 57344;
    stage2(Ahp, m0, 0, T00, c); stage2(Bhp, n0, 0, T02, c);
    stage2(Alp, m0, 0, T01, c); stage2(Blp, n0, 0, T03, c);
    VMCNT(4); SB0(); BAR();
    #pragma unroll 1
    for (int it = 0; it < 15; ++it) {
        step_gg<true>(Ahp, Alp, Bhp, Blp, m0, n0, (2 * it + 1) * 32, T00, T01, T02, T03, T10, T11, T12, T13, c, acc);
        step_gg<true>(Ahp, Alp, Bhp, Blp, m0, n0, (2 * it + 2) * 32, T10, T11, T12, T13, T00, T01, T02, T03, c, acc);
    }
    step_gg<true >(Ahp, Alp, Bhp, Blp, m0, n0, 31 * 32, T00, T01, T02, T03, T10, T11, T12, T13, c, acc);
    step_gg<false>(Ahp, Alp, Bhp, Blp, m0, n0, 0,       T10, T11, T12, T13, T00, T01, T02, T03, c, acc);
}

__global__ __launch_bounds__(512, 2) void g2k(const short* __restrict__ TQh, const short* __restrict__ TQl,
                                              const short* __restrict__ Kh, const short* __restrict__ Kl,
                                              const int* __restrict__ mask, float* __restrict__ alpha) {
    __shared__ __align__(16) short lds[65536];
    const int t = threadIdx.x;
    const int m0 = blockIdx.y * 256, n0 = blockIdx.x * 256, b = blockIdx.z;
    const Ctx c = make_ctx(t);
    float4v acc[4][8] = {};
    core_gg(TQh + (size_t)b * 1048576, TQl + (size_t)b * 1048576,
            Kh + (size_t)b * 1048576, Kl + (size_t)b * 1048576, m0, n0, lds, c, acc);
    int mk[8];
    #pragma unroll
    for (int nt = 0; nt < 8; ++nt)
        mk[nt] = mask[b * K_DIM + n0 + c.wn * 128 + nt * 16 + c.l15];
    #pragma unroll
    for (int mt = 0; mt < 4; ++mt)
        #pragma unroll
        for (int reg = 0; reg < 4; ++reg) {
            const int m = m0 + c.wm * 64 + mt * 16 + c.quad * 4 + reg;
            #pragma unroll
            for (int nt = 0; nt < 8; ++nt) {
                const int n = n0 + c.wn * 128 + nt * 16 + c.l15;
                alpha[((size_t)m * B_DIM + b) * K_DIM + n] = mk[nt] ? MASK_NEG : acc[mt][nt][reg];
            }
        }
}

// ---------------------------------------------------------------------------
// GEMM3 (per b): out[s][b][d] = sum_k P[s][k]*keys[b][k][d].
// A = alpha reg-staged + exp on the fly; B via gll16 from pre-transposed KT.
// (round-3 core: proven 118 us)  Invariant entering P0: Bl(s)=2.
// ---------------------------------------------------------------------------
template<bool DS>
__device__ __forceinline__ void step_g3(const float4* __restrict__ aP, int kn,
                                        const short* __restrict__ Bhp, const short* __restrict__ Blp, int n0,
                                        const short* C0, const short* C1, const short* C2, const short* C3,
                                        short* N0, short* N1, short* N2, short* N3,
                                        const Ctx& c, float Mv, float Lv,
                                        float4v (&acc)[4][8]) {
    short8v ah[4], bh[8];
    #pragma unroll
    for (int mt = 0; mt < 4; ++mt) ah[mt] = *(const short8v*)(C0 + c.offA[mt]);
    #pragma unroll
    for (int nt = 0; nt < 8; ++nt) bh[nt] = *(const short8v*)(C2 + c.offB[nt]);
    float4 va[4];
    if (DS) {
        #pragma unroll
        for (int i = 0; i < 4; ++i) va[i] = aP[kn / 4 + i];   // alpha(s+1) -> regs
        stage2(Bhp, n0, kn, N2, c);
    }
    SB0(); BAR(); LGKM0(); SB0();
    PRIO(1); mfma8x4(ah, bh, acc); PRIO(0); SB0(); BAR();

    short8v al[4];
    #pragma unroll
    for (int mt = 0; mt < 4; ++mt) al[mt] = *(const short8v*)(C1 + c.offA[mt]);
    if (DS) { stage2(Blp, n0, kn, N3, c); }
    SB0(); BAR(); LGKM0(); SB0();
    PRIO(1); mfma8x4(al, bh, acc); PRIO(0); SB0(); BAR();

    if (DS) { VMCNT(4); }   // drains Bl(s)+alpha; leaves Bh(s+1)2+Bl(s+1)2
    else    { VMCNT(0); }
    SB0(); BAR();
    short8v bl[8];
    #pragma unroll
    for (int nt = 0; nt < 8; ++nt) bl[nt] = *(const short8v*)(C3 + c.offB[nt]);
    LGKM0(); SB0();
    PRIO(1); mfma8x4(ah, bl, acc); PRIO(0);
    if (DS) {
        writeA_exp(va, Mv, Lv, N0, N1, c.ws0, c.ws1);   // A(s+1) -> LDS
        LGKM0();
        VMCNT(2);   // drains Bh(s+1) -> validates next P0; leaves Bl(s+1)=2
    }
    SB0(); BAR();
}

__global__ __launch_bounds__(512, 2) void g3k(const float* __restrict__ alpha,
                                              const short* __restrict__ KTh, const short* __restrict__ KTl,
                                              const float* __restrict__ mx, const float* __restrict__ il,
                                              float* __restrict__ outk) {
    __shared__ __align__(16) short lds[65536];
    const int t = threadIdx.x;
    const int m0 = blockIdx.y * 256, n0 = blockIdx.x * 256, b = blockIdx.z;
    const Ctx c = make_ctx(t);
    const short* Bhp = KTh + (size_t)b * 1048576;
    const short* Blp = KTl + (size_t)b * 1048576;
    const float4* aP = (const float4*)(alpha + ((size_t)(m0 + c.arow) * B_DIM + b) * K_DIM + c.ac * 16);
    const float Mv = mx[(size_t)(m0 + c.arow) * B_DIM + b];
    const float Lv = il[(size_t)(m0 + c.arow) * B_DIM + b];
    short *T00 = lds,         *T01 = lds + 8192,  *T02 = lds + 16384, *T03 = lds + 24576;
    short *T10 = lds + 32768, *T11 = lds + 40960, *T12 = lds + 49152, *T13 = lds + 57344;

    float4v acc[4][8] = {};
    {   // prologue: tile 0
        float4 va[4];
        #pragma unroll
        for (int i = 0; i < 4; ++i) va[i] = aP[i];
        stage2(Bhp, n0, 0, T02, c);
        stage2(Blp, n0, 0, T03, c);
        VMCNT(4);                      // alpha(0) arrived; Bh0+Bl0 in flight
        writeA_exp(va, Mv, Lv, T00, T01, c.ws0, c.ws1);
        LGKM0();
        VMCNT(2);                      // Bh(0) done; leaves Bl(0)=2
        SB0(); BAR();
    }
    #pragma unroll 1
    for (int it = 0; it < 15; ++it) {
        step_g3<true>(aP, (2 * it + 1) * 32, Bhp, Blp, n0, T00, T01, T02, T03, T10, T11, T12, T13, c, Mv, Lv, acc);
        step_g3<true>(aP, (2 * it + 2) * 32, Bhp, Blp, n0, T10, T11, T12, T13, T00, T01, T02, T03, c, Mv, Lv, acc);
    }
    step_g3<true >(aP, 31 * 32, Bhp, Blp, n0, T00, T01, T02, T03, T10, T11, T12, T13, c, Mv, Lv, acc);
    step_g3<false>(aP, 0,       Bhp, Blp, n0, T10, T11, T12, T13, T00, T01, T02, T03, c, Mv, Lv, acc);

    #pragma unroll
    for (int mt = 0; mt < 4; ++mt)
        #pragma unroll
        for (int reg = 0; reg < 4; ++reg) {
            const int m = m0 + c.wm * 64 + mt * 16 + c.quad * 4 + reg;
            #pragma unroll
            for (int nt = 0; nt < 8; ++nt) {
                const int n = n0 + c.wn * 128 + nt * 16 + c.l15;
                outk[((size_t)m * B_DIM + b) * KD_DIM + n] = acc[mt][nt][reg];
            }
        }
}

// ---------------------------------------------------------------------------
// Schedule / aliasing (ws use = proven 64 MiB + 128 KiB):
//   ws[0..64M):   TQh/TQl (g1 -> g2), then KTh/KTl (k_transpose after g2 -> g3)
//   ws[64M..):    mx/il
//   out_alpha:    Wh/Wl head 4 MiB (ksplit(W) -> g1), then real alpha (g2)
//   out_att:      Kh/Kl (ksplit(keys) -> g2), then real output (g3)
// ---------------------------------------------------------------------------
extern "C" void kernel_launch(void* const* d_in, const int* in_sizes, int n_in,
                              void* d_out, int out_size, void* d_ws, size_t ws_size,
                              hipStream_t stream) {
    const float* Q    = (const float*)d_in[0];   // (S, B, QD)
    const float* keys = (const float*)d_in[1];   // (B, K, KD)
    const int*   mask = (const int*)d_in[2];     // (B, K)
    const float* W    = (const float*)d_in[3];   // (KD, QD)

    float* out_att   = (float*)d_out;
    float* out_alpha = out_att + (size_t)S_DIM * B_DIM * KD_DIM;

    const size_t STREAM = (size_t)B_DIM * 1048576;   // shorts per big stream (32 MiB)

    short* TQh = (short*)d_ws;
    short* TQl = TQh + STREAM;
    short* KTh = (short*)d_ws;          // sequential reuse of TQ region (after g2)
    short* KTl = KTh + STREAM;
    float* mx  = (float*)((char*)d_ws + ((size_t)64 << 20));
    float* il  = mx + S_DIM * B_DIM;

    short* Wh  = (short*)out_alpha;     // dead after g1; g2 overwrites with alpha
    short* Wl  = Wh + 1048576;
    short* Khs = (short*)out_att;       // dead after g2; g3 overwrites with output
    short* Kls = Khs + STREAM;

    dim3 blk(256), blkg(512);

    k_split<<<dim3(1024), blk, 0, stream>>>(W, Wh, Wl);
    k_split<<<dim3(16384), blk, 0, stream>>>(keys, Khs, Kls);

    g1k<<<dim3(KD_DIM / 256, (S_DIM * B_DIM) / 256), blkg, 0, stream>>>(Q, Wh, Wl, TQh, TQl);

    g2k<<<dim3(K_DIM / 256, S_DIM / 256, B_DIM), blkg, 0, stream>>>(TQh, TQl, Khs, Kls, mask, out_alpha);

    k_transpose<<<dim3(32, 32, B_DIM), blk, 0, stream>>>(keys, KTh, KTl);   // TQ dead now

    k_stats<<<dim3(S_DIM * B_DIM), blk, 0, stream>>>(out_alpha, mx, il);

    g3k<<<dim3(KD_DIM / 256, S_DIM / 256, B_DIM), blkg, 0, stream>>>(out_alpha, KTh, KTl, mx, il, out_att);
}